// Round 14
// baseline (316.539 us; speedup 1.0000x reference)
//
#include <hip/hip_runtime.h>
#include <stdint.h>

typedef __bf16 bf16_t;
typedef __bf16 bf16x8 __attribute__((ext_vector_type(8)));
typedef float f32x4 __attribute__((ext_vector_type(4)));
typedef unsigned short us16x8 __attribute__((ext_vector_type(8)));

#define MFMA16(a, b, c) __builtin_amdgcn_mfma_f32_16x16x32_bf16(a, b, c, 0, 0, 0)
#define BAR() __builtin_amdgcn_s_barrier()
#define PRIO1() __builtin_amdgcn_s_setprio(1)
#define PRIO0() __builtin_amdgcn_s_setprio(0)
#define LGKM0()                                        \
  do {                                                 \
    asm volatile("s_waitcnt lgkmcnt(0)" ::: "memory"); \
    __builtin_amdgcn_sched_barrier(0);                 \
  } while (0)
#define VMCNT(n)                                          \
  do {                                                    \
    asm volatile("s_waitcnt vmcnt(" #n ")" ::: "memory"); \
    __builtin_amdgcn_sched_barrier(0);                    \
  } while (0)

__device__ __forceinline__ void stage16(const bf16_t* g, bf16_t* l) {
  __builtin_amdgcn_global_load_lds((__attribute__((address_space(1))) void*)g,
                                   (__attribute__((address_space(3))) void*)l, 16, 0, 0);
}

// ---------------- fused f32 -> bf16 conversion (x, w_attn, w_proj) ----------------
__global__ __launch_bounds__(256) void cvt_all(const float* __restrict__ x,
                                               const float* __restrict__ wa,
                                               const float* __restrict__ wp,
                                               bf16_t* __restrict__ xb,
                                               bf16_t* __restrict__ wab,
                                               bf16_t* __restrict__ wpb) {
  int i = blockIdx.x * 256 + threadIdx.x;
  const float* src;
  bf16_t* dst;
  if (i < 1048576) {
    src = x + (size_t)i * 8;
    dst = xb + (size_t)i * 8;
  } else if (i < 2621440) {
    size_t j = (size_t)(i - 1048576) * 8;
    src = wa + j;
    dst = wab + j;
  } else {
    size_t j = (size_t)(i - 2621440) * 8;
    src = wp + j;
    dst = wpb + j;
  }
  const f32x4* p = (const f32x4*)src;
  f32x4 a = p[0], b = p[1];
  bf16x8 o;
  o[0] = (bf16_t)a[0]; o[1] = (bf16_t)a[1]; o[2] = (bf16_t)a[2]; o[3] = (bf16_t)a[3];
  o[4] = (bf16_t)b[0]; o[5] = (bf16_t)b[1]; o[6] = (bf16_t)b[2]; o[7] = (bf16_t)b[3];
  *(bf16x8*)dst = o;
}

// ====== PERSISTENT 256x128-tile BK=32 NT GEMM (r9 exact, best measured) ======
template <int OUT_BF16>
__global__ __launch_bounds__(256, 2) void gemm_w128p(const bf16_t* __restrict__ A,
                                                     const bf16_t* __restrict__ B,
                                                     const float* __restrict__ bias,
                                                     void* __restrict__ Cout,
                                                     int M, int N, int K) {
  __shared__ bf16_t SA[3 * 256 * 32];
  __shared__ bf16_t SB[3 * 128 * 32];
  const int tid = threadIdx.x;
  const int l = tid & 63, w = tid >> 6;
  const int l15 = l & 15, l4 = l >> 4;
  const int wm = w >> 1, wn = w & 1;
  const int nbn = N >> 7;
  const int nbm = M >> 8;
  const int total = nbm * nbn;
  const int bnpc = nbn >> 3;

  const int r0 = tid >> 2;
  const int scol = (((tid & 3) ^ ((r0 >> 1) & 3)) << 3);
  const size_t K64 = (size_t)64 * K;

  const int swz = (l4 ^ ((l15 >> 1) & 3)) << 3;
  int aoff[8], boff[4];
#pragma unroll
  for (int i = 0; i < 8; ++i) aoff[i] = (wm * 128 + i * 16 + l15) * 32 + swz;
#pragma unroll
  for (int i = 0; i < 4; ++i) boff[i] = (wn * 64 + i * 16 + l15) * 32 + swz;

  const int nk = K >> 5;

  for (int wk = blockIdx.x; wk < total; wk += gridDim.x) {
    const int c = wk & 7, rr0 = wk >> 3;
    const int bm = rr0 / bnpc;
    const int bn = c * bnpc + rr0 % bnpc;

    const bf16_t* gA = A + (size_t)(bm * 256 + r0) * K + scol;
    const bf16_t* gB = B + (size_t)(bn * 128 + r0) * K + scol;

    f32x4 acc[8][4] = {};

    auto STAGE = [&](int t2, int buf) {
      const size_t ko = (size_t)t2 * 32;
      stage16(gA + ko, SA + buf * 8192 + tid * 8);
      stage16(gA + K64 + ko, SA + buf * 8192 + 2048 + tid * 8);
      stage16(gA + 2 * K64 + ko, SA + buf * 8192 + 4096 + tid * 8);
      stage16(gA + 3 * K64 + ko, SA + buf * 8192 + 6144 + tid * 8);
      stage16(gB + ko, SB + buf * 4096 + tid * 8);
      stage16(gB + K64 + ko, SB + buf * 4096 + 2048 + tid * 8);
    };

    auto TILE = [&](int t, int bufR, int bufS) {
      const int t2 = (t + 2 < nk) ? t + 2 : nk - 1;
      STAGE(t2, bufS);
      bf16x8 aR[8], bR[4];
#pragma unroll
      for (int i = 0; i < 8; ++i) aR[i] = *(const bf16x8*)(SA + bufR * 8192 + aoff[i]);
#pragma unroll
      for (int i = 0; i < 4; ++i) bR[i] = *(const bf16x8*)(SB + bufR * 4096 + boff[i]);
      VMCNT(6);
      BAR();
      LGKM0();
      PRIO1();
#pragma unroll
      for (int mi = 0; mi < 8; ++mi)
#pragma unroll
        for (int ni = 0; ni < 4; ++ni)
          acc[mi][ni] = MFMA16(aR[mi], bR[ni], acc[mi][ni]);
      PRIO0();
      BAR();
    };

    STAGE(0, 0);
    STAGE(1, 1);
    VMCNT(6);
    BAR();

    for (int t = 0; t < nk - 1; t += 3) {
      TILE(t, 0, 2);
      TILE(t + 1, 1, 0);
      TILE(t + 2, 2, 1);
    }
    TILE(nk - 1, 0, 2);
    VMCNT(0);

    const int rbase = bm * 256 + wm * 128 + (l4 << 2);
    const int cbase = bn * 128 + wn * 64 + l15;
#pragma unroll
    for (int ni = 0; ni < 4; ++ni) {
      float bv = bias[cbase + ni * 16];
#pragma unroll
      for (int mi = 0; mi < 8; ++mi)
#pragma unroll
        for (int rr = 0; rr < 4; ++rr) {
          float v = acc[mi][ni][rr] + bv;
          size_t off = (size_t)(rbase + mi * 16 + rr) * N + (cbase + ni * 16);
          if (OUT_BF16) ((bf16_t*)Cout)[off] = (bf16_t)v;
          else ((float*)Cout)[off] = v;
        }
    }
  }
}

// ---------------- causal flash attention: QBLK=128 (r1 body), paired dispatch ------
// 512 blocks, one q-tile of 128 rows each (4 waves x 32 rows). Mapping: bh = bid&31
// (h = bh&15 -> bid&7 = h&7: XCD holds 4 heads' K/V = 4MB, L2-resident); p = (bid>>5)&7;
// qt = (bid>>8) ? 15-p : p. Blocks bid and bid+256 (q-tiles p, 15-p) co-reside on one
// CU (2 blocks/CU, all 512 resident) -> per-CU work = (2p+2)+(32-2p) = 34 steps,
// uniform. Halves staging steps vs QBLK=64 (66 -> 34 per CU); attn is staging-
// latency-bound (MfmaUtil 4.6%) so time ~ halves. Serial staging per step (the r13
// double-buffer regressed; reverted).
__global__ __launch_bounds__(256, 2) void attn_fwd(const bf16_t* __restrict__ qkv,
                                                   bf16_t* __restrict__ att) {
  __shared__ bf16_t Kt[64 * 128];    // [krow][d], 16B-block-swizzled rows
  __shared__ bf16_t Vt[128 * 64];    // transposed [d][k], swizzled k-blocks
  __shared__ bf16_t Pl[4][32 * 72];  // per-wave P scratch, padded rows

  int bid = blockIdx.x;
  int bh = bid & 31;
  int h = bh & 15, b = bh >> 4;
  int p = (bid >> 5) & 7;
  int qt = (bid >> 8) ? 15 - p : p;
  int tid = threadIdx.x;
  int l = tid & 63, w = tid >> 6;
  int l15 = l & 15, l4 = l >> 4, l7 = l & 7;
  int q0 = qt << 7, wq0 = q0 + w * 32;
  const size_t LD = 6144;
  const bf16_t* base = qkv + (size_t)b * 2048 * LD;

  // Q fragments in registers: [m2][kk] (A-operand layout, 32 rows/wave)
  bf16x8 qf[2][4];
#pragma unroll
  for (int m2 = 0; m2 < 2; ++m2)
#pragma unroll
    for (int kk = 0; kk < 4; ++kk)
      qf[m2][kk] = *(const bf16x8*)(base + (size_t)(wq0 + m2 * 16 + l15) * LD +
                                    h * 128 + kk * 32 + l4 * 8);

  f32x4 acc[2][8] = {};
  float mrow[2][4], lrow[2][4];
#pragma unroll
  for (int m2 = 0; m2 < 2; ++m2)
#pragma unroll
    for (int r = 0; r < 4; ++r) { mrow[m2][r] = -1e30f; lrow[m2][r] = 0.f; }

  int nkt = 2 * qt + 2;
#pragma unroll 1
  for (int kt = 0; kt < nkt; ++kt) {
    int kb = kt << 6;
    // ---- V loads issued first (latency hides under K-issue + pack) ----
    const bf16_t* vg = base + (size_t)kb * LD + 4096 + h * 128;
    us16x8 va[2], vb[2];
#pragma unroll
    for (int pp = 0; pp < 2; ++pp) {
      int g = pp * 256 + tid;
      int kv = (g >> 4) << 1;
      int d0 = (g & 15) << 3;
      va[pp] = *(const us16x8*)(vg + (size_t)kv * LD + d0);
      vb[pp] = *(const us16x8*)(vg + (size_t)(kv + 1) * LD + d0);
    }
    // ---- K tile [64][128] via global_load_lds, source pre-swizzled ----
    const bf16_t* kg = base + (size_t)kb * LD + 2048 + h * 128;
#pragma unroll
    for (int i = 0; i < 4; ++i) {
      int e = i * 256 + tid;
      int row = e >> 4, blk = e & 15;
      int src = (blk ^ (row & 7)) << 3;
      stage16(kg + (size_t)row * LD + src, Kt + e * 8);
    }
    // ---- V transpose writes (packed b32, swizzled) ----
#pragma unroll
    for (int pp = 0; pp < 2; ++pp) {
      int g = pp * 256 + tid;
      int kv = (g >> 4) << 1;
      int d0 = (g & 15) << 3;
      int k8 = kv >> 3, kr = kv & 7;
#pragma unroll
      for (int j = 0; j < 8; ++j) {
        int d = d0 + j;
        int swzv = k8 ^ ((d ^ (d >> 3)) & 7);
        unsigned pack = (unsigned)va[pp][j] | ((unsigned)vb[pp][j] << 16);
        *(unsigned*)(&Vt[d * 64 + swzv * 8 + kr]) = pack;
      }
    }
    __syncthreads();

    if (kb < wq0 + 32) {  // wave-uniform: any unmasked element for this wave
      bool needMask = (kb + 63) > wq0;
      f32x4 s[2][4] = {};
      PRIO1();
#pragma unroll
      for (int kk = 0; kk < 4; ++kk) {
        int blk = (kk * 4 + l4) ^ l7;
#pragma unroll
        for (int n = 0; n < 4; ++n) {
          bf16x8 kf = *(const bf16x8*)(Kt + (n * 16 + l15) * 128 + blk * 8);
          s[0][n] = MFMA16(qf[0][kk], kf, s[0][n]);
          s[1][n] = MFMA16(qf[1][kk], kf, s[1][n]);
        }
      }
      PRIO0();
      const float sc = 0.08838834764831845f;  // 1/sqrt(128)
      float scf[2][4];
#pragma unroll
      for (int m2 = 0; m2 < 2; ++m2) {
#pragma unroll
        for (int r = 0; r < 4; ++r) {
          int q = wq0 + m2 * 16 + (l4 << 2) + r;
#pragma unroll
          for (int n = 0; n < 4; ++n) {
            float v = s[m2][n][r] * sc;
            if (needMask && (kb + n * 16 + l15) > q) v = -1e30f;
            s[m2][n][r] = v;
          }
          float mx = fmaxf(fmaxf(s[m2][0][r], s[m2][1][r]), fmaxf(s[m2][2][r], s[m2][3][r]));
          mx = fmaxf(mx, __shfl_xor(mx, 1));
          mx = fmaxf(mx, __shfl_xor(mx, 2));
          mx = fmaxf(mx, __shfl_xor(mx, 4));
          mx = fmaxf(mx, __shfl_xor(mx, 8));
          float mn = fmaxf(mrow[m2][r], mx);
          float sf = __expf(mrow[m2][r] - mn);
          mrow[m2][r] = mn;
          scf[m2][r] = sf;
          float rs = 0.f;
#pragma unroll
          for (int n = 0; n < 4; ++n) {
            float pv = __expf(s[m2][n][r] - mn);
            s[m2][n][r] = pv;
            rs += pv;
          }
          rs += __shfl_xor(rs, 1);
          rs += __shfl_xor(rs, 2);
          rs += __shfl_xor(rs, 4);
          rs += __shfl_xor(rs, 8);
          lrow[m2][r] = lrow[m2][r] * sf + rs;
        }
      }
      // rescale accumulator
#pragma unroll
      for (int m2 = 0; m2 < 2; ++m2)
#pragma unroll
        for (int nd = 0; nd < 8; ++nd)
#pragma unroll
          for (int r = 0; r < 4; ++r)
            acc[m2][nd][r] *= scf[m2][r];
      // P (C-layout) -> LDS -> A-layout fragments
#pragma unroll
      for (int m2 = 0; m2 < 2; ++m2)
#pragma unroll
        for (int n = 0; n < 4; ++n)
#pragma unroll
          for (int r = 0; r < 4; ++r)
            Pl[w][(m2 * 16 + (l4 << 2) + r) * 72 + n * 16 + l15] = (bf16_t)s[m2][n][r];
      // PV
      PRIO1();
#pragma unroll
      for (int kk2 = 0; kk2 < 2; ++kk2) {
        bf16x8 pa0 = *(const bf16x8*)(&Pl[w][l15 * 72 + kk2 * 32 + l4 * 8]);
        bf16x8 pa1 = *(const bf16x8*)(&Pl[w][(16 + l15) * 72 + kk2 * 32 + l4 * 8]);
#pragma unroll
        for (int nd = 0; nd < 8; ++nd) {
          int d = nd * 16 + l15;
          int swzv = (kk2 * 4 + l4) ^ ((d ^ (d >> 3)) & 7);
          bf16x8 bv = *(const bf16x8*)(&Vt[d * 64 + swzv * 8]);
          acc[0][nd] = MFMA16(pa0, bv, acc[0][nd]);
          acc[1][nd] = MFMA16(pa1, bv, acc[1][nd]);
        }
      }
      PRIO0();
    }
    __syncthreads();
  }

  // epilogue: O /= l, write bf16
#pragma unroll
  for (int m2 = 0; m2 < 2; ++m2)
#pragma unroll
    for (int r = 0; r < 4; ++r) {
      float inv = 1.0f / lrow[m2][r];
      size_t ro = (size_t)(b * 2048 + wq0 + m2 * 16 + (l4 << 2) + r) * 2048 + h * 128;
#pragma unroll
      for (int nd = 0; nd < 8; ++nd)
        att[ro + nd * 16 + l15] = (bf16_t)(acc[m2][nd][r] * inv);
    }
}

// ---------------- launch ----------------
extern "C" void kernel_launch(void* const* d_in, const int* in_sizes, int n_in,
                              void* d_out, int out_size, void* d_ws, size_t ws_size,
                              hipStream_t stream) {
  (void)in_sizes; (void)n_in; (void)out_size; (void)ws_size;
  const float* x = (const float*)d_in[0];
  const float* w_attn = (const float*)d_in[1];
  const float* b_attn = (const float*)d_in[2];
  const float* w_proj = (const float*)d_in[3];
  const float* b_proj = (const float*)d_in[4];
  float* out = (float*)d_out;

  char* ws = (char*)d_ws;
  bf16_t* xb  = (bf16_t*)(ws);
  bf16_t* wab = (bf16_t*)(ws + 16777216);
  bf16_t* wpb = (bf16_t*)(ws + 41943040);
  bf16_t* qkv = (bf16_t*)(ws + 50331648);
  bf16_t* att = xb;  // xb dead after GEMM1

  // fused conversions: 3,145,728 vec8 -> 12288 blocks
  cvt_all<<<12288, 256, 0, stream>>>(x, w_attn, w_proj, xb, wab, wpb);

  // qkv = x @ w_attn^T + b_attn -> bf16 [4096, 6144]  (r9 persistent, 512 blocks)
  gemm_w128p<1><<<512, 256, 0, stream>>>(xb, wab, b_attn, qkv, 4096, 6144, 2048);

  // causal flash attention -> att bf16 [4096, 2048]  (QBLK=128, paired dispatch)
  attn_fwd<<<512, 256, 0, stream>>>(qkv, att);

  // out = att @ w_proj^T + b_proj -> f32 [4096, 2048]  (r9 persistent)
  gemm_w128p<0><<<512, 256, 0, stream>>>(att, wpb, b_proj, out, 4096, 2048, 2048);
}

// Round 15
// 300.197 us; speedup vs baseline: 1.0544x; 1.0544x over previous
//
#include <hip/hip_runtime.h>
#include <stdint.h>

typedef __bf16 bf16_t;
typedef __bf16 bf16x8 __attribute__((ext_vector_type(8)));
typedef float f32x4 __attribute__((ext_vector_type(4)));
typedef unsigned short us16x8 __attribute__((ext_vector_type(8)));

#define MFMA16(a, b, c) __builtin_amdgcn_mfma_f32_16x16x32_bf16(a, b, c, 0, 0, 0)
#define BAR() __builtin_amdgcn_s_barrier()
#define PRIO1() __builtin_amdgcn_s_setprio(1)
#define PRIO0() __builtin_amdgcn_s_setprio(0)
#define LGKM0()                                        \
  do {                                                 \
    asm volatile("s_waitcnt lgkmcnt(0)" ::: "memory"); \
    __builtin_amdgcn_sched_barrier(0);                 \
  } while (0)
#define VMCNT(n)                                          \
  do {                                                    \
    asm volatile("s_waitcnt vmcnt(" #n ")" ::: "memory"); \
    __builtin_amdgcn_sched_barrier(0);                    \
  } while (0)

__device__ __forceinline__ void stage16(const bf16_t* g, bf16_t* l) {
  __builtin_amdgcn_global_load_lds((__attribute__((address_space(1))) void*)g,
                                   (__attribute__((address_space(3))) void*)l, 16, 0, 0);
}

// ---------------- fused f32 -> bf16 conversion (x, w_attn, w_proj) ----------------
__global__ __launch_bounds__(256) void cvt_all(const float* __restrict__ x,
                                               const float* __restrict__ wa,
                                               const float* __restrict__ wp,
                                               bf16_t* __restrict__ xb,
                                               bf16_t* __restrict__ wab,
                                               bf16_t* __restrict__ wpb) {
  int i = blockIdx.x * 256 + threadIdx.x;
  const float* src;
  bf16_t* dst;
  if (i < 1048576) {
    src = x + (size_t)i * 8;
    dst = xb + (size_t)i * 8;
  } else if (i < 2621440) {
    size_t j = (size_t)(i - 1048576) * 8;
    src = wa + j;
    dst = wab + j;
  } else {
    size_t j = (size_t)(i - 2621440) * 8;
    src = wp + j;
    dst = wpb + j;
  }
  const f32x4* p = (const f32x4*)src;
  f32x4 a = p[0], b = p[1];
  bf16x8 o;
  o[0] = (bf16_t)a[0]; o[1] = (bf16_t)a[1]; o[2] = (bf16_t)a[2]; o[3] = (bf16_t)a[3];
  o[4] = (bf16_t)b[0]; o[5] = (bf16_t)b[1]; o[6] = (bf16_t)b[2]; o[7] = (bf16_t)b[3];
  *(bf16x8*)dst = o;
}

// ====== PERSISTENT 256x128-tile BK=32 NT GEMM (r9 exact, best measured) ======
template <int OUT_BF16>
__global__ __launch_bounds__(256, 2) void gemm_w128p(const bf16_t* __restrict__ A,
                                                     const bf16_t* __restrict__ B,
                                                     const float* __restrict__ bias,
                                                     void* __restrict__ Cout,
                                                     int M, int N, int K) {
  __shared__ bf16_t SA[3 * 256 * 32];
  __shared__ bf16_t SB[3 * 128 * 32];
  const int tid = threadIdx.x;
  const int l = tid & 63, w = tid >> 6;
  const int l15 = l & 15, l4 = l >> 4;
  const int wm = w >> 1, wn = w & 1;
  const int nbn = N >> 7;
  const int nbm = M >> 8;
  const int total = nbm * nbn;
  const int bnpc = nbn >> 3;

  const int r0 = tid >> 2;
  const int scol = (((tid & 3) ^ ((r0 >> 1) & 3)) << 3);
  const size_t K64 = (size_t)64 * K;

  const int swz = (l4 ^ ((l15 >> 1) & 3)) << 3;
  int aoff[8], boff[4];
#pragma unroll
  for (int i = 0; i < 8; ++i) aoff[i] = (wm * 128 + i * 16 + l15) * 32 + swz;
#pragma unroll
  for (int i = 0; i < 4; ++i) boff[i] = (wn * 64 + i * 16 + l15) * 32 + swz;

  const int nk = K >> 5;

  for (int wk = blockIdx.x; wk < total; wk += gridDim.x) {
    const int c = wk & 7, rr0 = wk >> 3;
    const int bm = rr0 / bnpc;
    const int bn = c * bnpc + rr0 % bnpc;

    const bf16_t* gA = A + (size_t)(bm * 256 + r0) * K + scol;
    const bf16_t* gB = B + (size_t)(bn * 128 + r0) * K + scol;

    f32x4 acc[8][4] = {};

    auto STAGE = [&](int t2, int buf) {
      const size_t ko = (size_t)t2 * 32;
      stage16(gA + ko, SA + buf * 8192 + tid * 8);
      stage16(gA + K64 + ko, SA + buf * 8192 + 2048 + tid * 8);
      stage16(gA + 2 * K64 + ko, SA + buf * 8192 + 4096 + tid * 8);
      stage16(gA + 3 * K64 + ko, SA + buf * 8192 + 6144 + tid * 8);
      stage16(gB + ko, SB + buf * 4096 + tid * 8);
      stage16(gB + K64 + ko, SB + buf * 4096 + 2048 + tid * 8);
    };

    auto TILE = [&](int t, int bufR, int bufS) {
      const int t2 = (t + 2 < nk) ? t + 2 : nk - 1;
      STAGE(t2, bufS);
      bf16x8 aR[8], bR[4];
#pragma unroll
      for (int i = 0; i < 8; ++i) aR[i] = *(const bf16x8*)(SA + bufR * 8192 + aoff[i]);
#pragma unroll
      for (int i = 0; i < 4; ++i) bR[i] = *(const bf16x8*)(SB + bufR * 4096 + boff[i]);
      VMCNT(6);
      BAR();
      LGKM0();
      PRIO1();
#pragma unroll
      for (int mi = 0; mi < 8; ++mi)
#pragma unroll
        for (int ni = 0; ni < 4; ++ni)
          acc[mi][ni] = MFMA16(aR[mi], bR[ni], acc[mi][ni]);
      PRIO0();
      BAR();
    };

    STAGE(0, 0);
    STAGE(1, 1);
    VMCNT(6);
    BAR();

    for (int t = 0; t < nk - 1; t += 3) {
      TILE(t, 0, 2);
      TILE(t + 1, 1, 0);
      TILE(t + 2, 2, 1);
    }
    TILE(nk - 1, 0, 2);
    VMCNT(0);

    const int rbase = bm * 256 + wm * 128 + (l4 << 2);
    const int cbase = bn * 128 + wn * 64 + l15;
#pragma unroll
    for (int ni = 0; ni < 4; ++ni) {
      float bv = bias[cbase + ni * 16];
#pragma unroll
      for (int mi = 0; mi < 8; ++mi)
#pragma unroll
        for (int rr = 0; rr < 4; ++rr) {
          float v = acc[mi][ni][rr] + bv;
          size_t off = (size_t)(rbase + mi * 16 + rr) * N + (cbase + ni * 16);
          if (OUT_BF16) ((bf16_t*)Cout)[off] = (bf16_t)v;
          else ((float*)Cout)[off] = v;
        }
    }
  }
}

// ------- causal flash attention: r2 body (QBLK=64, in-block pair) + K/V dbuf -------
// Block = (pair i, b, h): q-tile i then 31-i, 4 waves x 16 rows -> uniform 33 steps.
// bid%8 = h%8 -> XCD-local K/V (4 heads = 4MB, L2-resident).
// NEW (guard kept, unlike r13): per step, issue V-reg-loads + K global_load_lds for
// t+1 into buf^1 BEFORE QK^T; after guarded QK^T+softmax, VMCNT(4) certifies V
// (issued oldest) and ds_write V; PV on buf; __syncthreads (implicit vmcnt(0))
// lands ~1500cyc after K issue -> K latency hidden. Staging unguarded (all waves).
// LDS: Kt[2]16K+Vt[2]16K... = 72KB -> 2 blocks/CU.
__global__ __launch_bounds__(256, 2) void attn_fwd(const bf16_t* __restrict__ qkv,
                                                   bf16_t* __restrict__ att) {
  __shared__ bf16_t Kt[2][64 * 128];
  __shared__ bf16_t Vt[2][128 * 64];
  __shared__ bf16_t Pw[4][16 * 64];

  int bid = blockIdx.x;
  int pair = bid >> 5, bh = bid & 31;
  int h = bh & 15, b = bh >> 4;
  int tid = threadIdx.x;
  int l = tid & 63, w = tid >> 6;
  int l15 = l & 15, l4 = l >> 4, l7 = l & 7;
  const size_t LD = 6144;
  const bf16_t* base = qkv + (size_t)b * 2048 * LD;

  us16x8 va[2], vb[2];

  auto loadV = [&](int kb) {
    const bf16_t* vg = base + (size_t)kb * LD + 4096 + h * 128;
#pragma unroll
    for (int p = 0; p < 2; ++p) {
      int g = p * 256 + tid;
      int kv = (g >> 4) << 1;
      int d0 = (g & 15) << 3;
      va[p] = *(const us16x8*)(vg + (size_t)kv * LD + d0);
      vb[p] = *(const us16x8*)(vg + (size_t)(kv + 1) * LD + d0);
    }
  };
  auto stageK = [&](int kb, int buf) {
    const bf16_t* kg = base + (size_t)kb * LD + 2048 + h * 128;
#pragma unroll
    for (int i = 0; i < 4; ++i) {
      int e = i * 256 + tid;
      int row = e >> 4, blk = e & 15;
      int src = (blk ^ (row & 7)) << 3;
      stage16(kg + (size_t)row * LD + src, &Kt[buf][e * 8]);
    }
  };
  auto writeV = [&](int buf) {
#pragma unroll
    for (int p = 0; p < 2; ++p) {
      int g = p * 256 + tid;
      int kv = (g >> 4) << 1;
      int d0 = (g & 15) << 3;
      int k8 = kv >> 3, kr = kv & 7;
#pragma unroll
      for (int j = 0; j < 8; ++j) {
        int d = d0 + j;
        int swzv = k8 ^ ((d ^ (d >> 3)) & 7);
        unsigned pack = (unsigned)va[p][j] | ((unsigned)vb[p][j] << 16);
        *(unsigned*)(&Vt[buf][d * 64 + swzv * 8 + kr]) = pack;
      }
    }
  };

#pragma unroll 1
  for (int phase = 0; phase < 2; ++phase) {
    int qt = phase ? 31 - pair : pair;
    int q0 = qt << 6;
    int wq0 = q0 + w * 16;

    bf16x8 qf[4];
#pragma unroll
    for (int kk = 0; kk < 4; ++kk)
      qf[kk] = *(const bf16x8*)(base + (size_t)(wq0 + l15) * LD + h * 128 + kk * 32 + l4 * 8);

    f32x4 acc[8] = {};
    float mrow[4], lrow[4];
#pragma unroll
    for (int r = 0; r < 4; ++r) { mrow[r] = -1e30f; lrow[r] = 0.f; }

    int nkt = qt + 1;

    // ---- phase prologue: V0 loads (issued first = oldest), K0 stage ----
    loadV(0);
    stageK(0, 0);
    VMCNT(4);  // V0 done (K0 still flying)
    writeV(0);
    __syncthreads();  // drains K0 DMA + V0 ds_writes

#pragma unroll 1
    for (int kt = 0; kt < nkt; ++kt) {
      const int cur = kt & 1, nxt = cur ^ 1;
      const bool pf = (kt + 1 < nkt);
      const int kb = kt << 6;
      const bool guard = kb < wq0 + 32;  // wave-uniform

      if (pf) {  // prefetch t+1: V first (oldest), then K DMA into buf^1
        loadV(kb + 64);
        stageK(kb + 64, nxt);
      }

      f32x4 s[4] = {};
      float scf[4];
      if (guard) {
        PRIO1();
#pragma unroll
        for (int kk = 0; kk < 4; ++kk) {
          int blk = (kk * 4 + l4) ^ l7;
#pragma unroll
          for (int n = 0; n < 4; ++n) {
            bf16x8 kf = *(const bf16x8*)(&Kt[cur][(n * 16 + l15) * 128 + blk * 8]);
            s[n] = MFMA16(qf[kk], kf, s[n]);
          }
        }
        PRIO0();

        const float sc = 0.08838834764831845f;
        bool needMask = (kb + 63) > wq0;
#pragma unroll
        for (int r = 0; r < 4; ++r) {
          int q = wq0 + (l4 << 2) + r;
#pragma unroll
          for (int n = 0; n < 4; ++n) {
            float v = s[n][r] * sc;
            if (needMask && (kb + n * 16 + l15) > q) v = -1e30f;
            s[n][r] = v;
          }
          float mx = fmaxf(fmaxf(s[0][r], s[1][r]), fmaxf(s[2][r], s[3][r]));
          mx = fmaxf(mx, __shfl_xor(mx, 1));
          mx = fmaxf(mx, __shfl_xor(mx, 2));
          mx = fmaxf(mx, __shfl_xor(mx, 4));
          mx = fmaxf(mx, __shfl_xor(mx, 8));
          float mn = fmaxf(mrow[r], mx);
          float sf = __expf(mrow[r] - mn);
          mrow[r] = mn;
          scf[r] = sf;
          float rs = 0.f;
#pragma unroll
          for (int n = 0; n < 4; ++n) {
            float pv = __expf(s[n][r] - mn);
            s[n][r] = pv;
            rs += pv;
          }
          rs += __shfl_xor(rs, 1);
          rs += __shfl_xor(rs, 2);
          rs += __shfl_xor(rs, 4);
          rs += __shfl_xor(rs, 8);
          lrow[r] = lrow[r] * sf + rs;
        }
      }

      // ---- V(t+1) write: VMCNT(4) certifies the 4 V loads (oldest); per-wave ----
      if (pf) {
        VMCNT(4);
        writeV(nxt);
      }

      if (guard) {
#pragma unroll
        for (int nd = 0; nd < 8; ++nd)
#pragma unroll
          for (int r = 0; r < 4; ++r)
            acc[nd][r] *= scf[r];
#pragma unroll
        for (int n = 0; n < 4; ++n) {
          int cb8 = n * 2 + (l15 >> 3);
#pragma unroll
          for (int r = 0; r < 4; ++r) {
            int row = (l4 << 2) + r;
            Pw[w][row * 64 + ((cb8 ^ (row & 7)) << 3) + l7] = (bf16_t)s[n][r];
          }
        }
        PRIO1();
#pragma unroll
        for (int kk2 = 0; kk2 < 2; ++kk2) {
          bf16x8 pa = *(const bf16x8*)(&Pw[w][l15 * 64 + (((kk2 * 4 + l4) ^ l7) << 3)]);
#pragma unroll
          for (int nd = 0; nd < 8; ++nd) {
            int d = nd * 16 + l15;
            int swzv = (kk2 * 4 + l4) ^ ((d ^ (d >> 3)) & 7);
            bf16x8 bv = *(const bf16x8*)(&Vt[cur][d * 64 + swzv * 8]);
            acc[nd] = MFMA16(pa, bv, acc[nd]);
          }
        }
        PRIO0();
      }
      __syncthreads();  // implicit vmcnt(0)+lgkmcnt(0): K(t+1) certified (hidden)
    }

#pragma unroll
    for (int r = 0; r < 4; ++r) {
      float inv = 1.0f / lrow[r];
      size_t ro = (size_t)(b * 2048 + wq0 + (l4 << 2) + r) * 2048 + h * 128;
#pragma unroll
      for (int nd = 0; nd < 8; ++nd)
        att[ro + nd * 16 + l15] = (bf16_t)(acc[nd][r] * inv);
    }
  }
}

// ---------------- launch ----------------
extern "C" void kernel_launch(void* const* d_in, const int* in_sizes, int n_in,
                              void* d_out, int out_size, void* d_ws, size_t ws_size,
                              hipStream_t stream) {
  (void)in_sizes; (void)n_in; (void)out_size; (void)ws_size;
  const float* x = (const float*)d_in[0];
  const float* w_attn = (const float*)d_in[1];
  const float* b_attn = (const float*)d_in[2];
  const float* w_proj = (const float*)d_in[3];
  const float* b_proj = (const float*)d_in[4];
  float* out = (float*)d_out;

  char* ws = (char*)d_ws;
  bf16_t* xb  = (bf16_t*)(ws);
  bf16_t* wab = (bf16_t*)(ws + 16777216);
  bf16_t* wpb = (bf16_t*)(ws + 41943040);
  bf16_t* qkv = (bf16_t*)(ws + 50331648);
  bf16_t* att = xb;  // xb dead after GEMM1

  // fused conversions
  cvt_all<<<12288, 256, 0, stream>>>(x, w_attn, w_proj, xb, wab, wpb);

  // qkv = x @ w_attn^T + b_attn -> bf16 [4096, 6144]  (r9 persistent, 512 blocks)
  gemm_w128p<1><<<512, 256, 0, stream>>>(xb, wab, b_attn, qkv, 4096, 6144, 2048);

  // causal flash attention -> att bf16 [4096, 2048]  (r2 pairing + K/V dbuf)
  attn_fwd<<<512, 256, 0, stream>>>(qkv, att);

  // out = att @ w_proj^T + b_proj -> f32 [4096, 2048]  (256 tiles, exact grid)
  gemm_w128p<0><<<256, 256, 0, stream>>>(att, wpb, b_proj, out, 4096, 2048, 2048);
}